// Round 16
// baseline (475.454 us; speedup 1.0000x reference)
//
#include <hip/hip_runtime.h>
#include <hip/hip_bf16.h>

// ---------------------------------------------------------------------------
// TokenFlowModel block on MI355X (gfx950).  Round 16.
// = Round 13 (best: 446us) with ONE change: attention swapped to the
//   round-5 variant (proven correct in r5, masked there by a GEMM
//   regression): 4 waves = 2 heads x 2 q-subtiles, no kv-split stream,
//   no end-combine, 1 kv-tile/superstep stage-ahead double buffer,
//   grid (8 kvh, 32 slabs LPT).  Removes the combine phase and halves
//   per-barrier staged bytes.
// Everything else byte-identical to round 13.
// ---------------------------------------------------------------------------

typedef __attribute__((ext_vector_type(8))) short short8;   // 8 x bf16
typedef __attribute__((ext_vector_type(4))) float f32x4;
typedef __attribute__((ext_vector_type(16))) float f32x16;
typedef __attribute__((ext_vector_type(4))) unsigned short u16x4;

#define MFMA16(a, b, c) __builtin_amdgcn_mfma_f32_16x16x32_bf16((a), (b), (c), 0, 0, 0)
#define MFMA32(a, b, c) __builtin_amdgcn_mfma_f32_32x32x16_bf16((a), (b), (c), 0, 0, 0)

__device__ __forceinline__ unsigned short f2b_bits(float f) {
    union { float f; unsigned int u; } cv; cv.f = f;
    unsigned int u = cv.u;
    u += 0x7fffu + ((u >> 16) & 1u);   // round-to-nearest-even
    return (unsigned short)(u >> 16);
}
__device__ __forceinline__ float b2f_bits(unsigned short b) {
    union { float f; unsigned int u; } cv; cv.u = ((unsigned int)b) << 16; return cv.f;
}
__device__ __forceinline__ float silu_f(float x) { return x / (1.0f + __expf(-x)); }

// async global->LDS, 16B per lane.  LDS dest: wave-uniform base + lane*16.
__device__ __forceinline__ void async_copy16(const unsigned short* g, unsigned short* l) {
    __builtin_amdgcn_global_load_lds(
        (const __attribute__((address_space(1))) unsigned int*)g,
        (__attribute__((address_space(3))) unsigned int*)l, 16, 0, 0);
}

// ---------------------------------------------------------------------------
// Transpose core: one 64x64 tile of W[K][N] f32 -> WT[N][K] bf16 (+scale)
// ---------------------------------------------------------------------------
__device__ __forceinline__ void transpose_tile(
    const float* __restrict__ W, unsigned short* __restrict__ WT,
    int K, int N, int k0, int n0, float scale, float t[64][65])
{
    const int tid = threadIdx.x;
    {
        const int row = tid >> 2, cq = (tid & 3) * 16;
        const float* src = W + (size_t)(k0 + row) * N + n0 + cq;
        #pragma unroll
        for (int i = 0; i < 4; i++) {
            float4 v = *(const float4*)(src + i * 4);
            t[row][cq + i * 4 + 0] = v.x;
            t[row][cq + i * 4 + 1] = v.y;
            t[row][cq + i * 4 + 2] = v.z;
            t[row][cq + i * 4 + 3] = v.w;
        }
    }
    __syncthreads();
    {
        const int n = tid >> 2, kq = (tid & 3) * 16;
        short8 v0, v1;
        #pragma unroll
        for (int i = 0; i < 8; i++) {
            v0[i] = (short)f2b_bits(t[kq + i][n] * scale);
            v1[i] = (short)f2b_bits(t[kq + 8 + i][n] * scale);
        }
        unsigned short* dst = WT + (size_t)(n0 + n) * K + k0 + kq;
        *(short8*)(dst) = v0;
        *(short8*)(dst + 8) = v1;
    }
}

__global__ __launch_bounds__(256) void transpose_kernel(
    const float* __restrict__ W, unsigned short* __restrict__ WT, int K, int N,
    float scale)
{
    __shared__ float t[64][65];
    transpose_tile(W, WT, K, N, blockIdx.y * 64, blockIdx.x * 64, scale, t);
}

// Fused QKV transpose: x<32 -> wq (scaled), 32<=x<48 -> wk, x>=48 -> wv.
__global__ __launch_bounds__(256) void transpose_qkv_kernel(
    const float* __restrict__ wq, const float* __restrict__ wk,
    const float* __restrict__ wv, unsigned short* __restrict__ WTqkv,
    float qscale)
{
    __shared__ float t[64][65];
    const int x = blockIdx.x, k0 = blockIdx.y * 64;
    if (x < 32) {
        transpose_tile(wq, WTqkv, 2048, 2048, k0, x * 64, qscale, t);
    } else if (x < 48) {
        transpose_tile(wk, WTqkv + (size_t)2048 * 2048, 2048, 1024, k0, (x - 32) * 64, 1.0f, t);
    } else {
        transpose_tile(wv, WTqkv + (size_t)3072 * 2048, 2048, 1024, k0, (x - 48) * 64, 1.0f, t);
    }
}

// Fused W1/W3 transpose via z.
__global__ __launch_bounds__(256) void transpose_w13_kernel(
    const float* __restrict__ w1, const float* __restrict__ w3,
    unsigned short* __restrict__ WT1, unsigned short* __restrict__ WT3)
{
    __shared__ float t[64][65];
    const float* W = blockIdx.z ? w3 : w1;
    unsigned short* WT = blockIdx.z ? WT3 : WT1;
    transpose_tile(W, WT, 2048, 5632, blockIdx.y * 64, blockIdx.x * 64, 1.0f, t);
}

// ---------------------------------------------------------------------------
// mod GEMM pass 1 (silu fused into the svec load): part[kc][m][6144]
// ---------------------------------------------------------------------------
__global__ __launch_bounds__(256) void mod_gemm1(
    const float* __restrict__ vec, const float* __restrict__ mw,
    float* __restrict__ part)
{
    __shared__ float svs[8][256];
    const int tid = threadIdx.x;
    const int nb = blockIdx.x, kc = blockIdx.y;
    const int n = nb * 256 + tid;
    #pragma unroll
    for (int m8 = 0; m8 < 8; m8++) svs[m8][tid] = silu_f(vec[m8 * 2048 + kc * 256 + tid]);
    __syncthreads();
    float acc[8];
    #pragma unroll
    for (int m = 0; m < 8; m++) acc[m] = 0.0f;
    for (int k = 0; k < 256; k++) {
        const float w = mw[(size_t)(kc * 256 + k) * 6144 + n];
        #pragma unroll
        for (int m = 0; m < 8; m++) acc[m] += svs[m][k] * w;
    }
    #pragma unroll
    for (int m = 0; m < 8; m++) part[(size_t)(kc * 8 + m) * 6144 + n] = acc[m];
}

__global__ void mod_gemm2(const float* __restrict__ part, const float* __restrict__ mb,
                          float* __restrict__ modb)
{
    const int i = blockIdx.x * 256 + threadIdx.x;   // 8*6144
    const int n = i % 6144;
    float a = mb[n];
    #pragma unroll
    for (int kc = 0; kc < 8; kc++) a += part[(size_t)(kc * 8 + (i / 6144)) * 6144 + n];
    modb[i] = a;
}

// ---------------------------------------------------------------------------
// RMSNorm + AdaLN modulation -> bf16 row.  One block per row.
// ---------------------------------------------------------------------------
__global__ __launch_bounds__(256) void norm_mod_kernel(
    const float* __restrict__ xin, const float* __restrict__ w,
    const float* __restrict__ mod, unsigned short* __restrict__ outp)
{
    const int s = blockIdx.x, tid = threadIdx.x;
    const float* xr = xin + (size_t)s * 2048;
    float4 a4 = *(const float4*)(xr + tid * 8);
    float4 b4 = *(const float4*)(xr + tid * 8 + 4);
    float v[8] = {a4.x, a4.y, a4.z, a4.w, b4.x, b4.y, b4.z, b4.w};
    float ss = 0.0f;
    #pragma unroll
    for (int i = 0; i < 8; i++) ss += v[i] * v[i];
    #pragma unroll
    for (int off = 1; off < 64; off <<= 1) ss += __shfl_xor(ss, off);
    __shared__ float red[4];
    if ((tid & 63) == 0) red[tid >> 6] = ss;
    __syncthreads();
    ss = red[0] + red[1] + red[2] + red[3];
    const float inv = rsqrtf(ss * (1.0f / 2048.0f) + 1e-6f);
    const int g = s >> 8;
    #pragma unroll
    for (int i = 0; i < 8; i++) {
        const int d = tid * 8 + i;
        float y = v[i] * inv * w[d];
        y = y * (1.0f + mod[g * 6144 + 2048 + d]) + mod[g * 6144 + d];
        outp[(size_t)s * 2048 + d] = f2b_bits(y);
    }
}

// ---------------------------------------------------------------------------
// Fused: out = x + gate*(p0+p1) ;  hn = rmsnorm(out)*fnw  (one pass per row)
// ---------------------------------------------------------------------------
__global__ __launch_bounds__(256) void combine_norm_kernel(
    const float* __restrict__ p, const float* __restrict__ x,
    const float* __restrict__ modp, const float* __restrict__ fnw,
    float* __restrict__ out, unsigned short* __restrict__ hn)
{
    const int s = blockIdx.x, tid = threadIdx.x;
    const int g = s >> 8;
    const size_t base = (size_t)s * 2048 + tid * 8;
    float v[8];
    #pragma unroll
    for (int i = 0; i < 8; i += 4) {
        const float4 a  = *(const float4*)(p + base + i);
        const float4 b  = *(const float4*)(p + (size_t)2048 * 2048 + base + i);
        const float4 xv = *(const float4*)(x + base + i);
        const float4 gv = *(const float4*)(modp + g * 6144 + 4096 + tid * 8 + i);
        v[i + 0] = xv.x + gv.x * (a.x + b.x);
        v[i + 1] = xv.y + gv.y * (a.y + b.y);
        v[i + 2] = xv.z + gv.z * (a.z + b.z);
        v[i + 3] = xv.w + gv.w * (a.w + b.w);
    }
    *(float4*)(out + base)     = (float4){v[0], v[1], v[2], v[3]};
    *(float4*)(out + base + 4) = (float4){v[4], v[5], v[6], v[7]};
    float ss = 0.0f;
    #pragma unroll
    for (int i = 0; i < 8; i++) ss += v[i] * v[i];
    #pragma unroll
    for (int off = 1; off < 64; off <<= 1) ss += __shfl_xor(ss, off);
    __shared__ float red[4];
    if ((tid & 63) == 0) red[tid >> 6] = ss;
    __syncthreads();
    ss = red[0] + red[1] + red[2] + red[3];
    const float inv = rsqrtf(ss * (1.0f / 2048.0f) + 1e-6f);
    #pragma unroll
    for (int i = 0; i < 8; i++) {
        const int d = tid * 8 + i;
        hn[(size_t)s * 2048 + d] = f2b_bits(v[i] * inv * fnw[d]);
    }
}

// ---------------------------------------------------------------------------
// bf16 GEMM, 2-phase double-buffered (proven core).
// 128x128 tile, BK=32, gload_lds width-16, XOR chunk swizzle, XCD swizzle.
// ---------------------------------------------------------------------------
enum { EP_QKV = 0, EP_BF16 = 1, EP_SILUMUL = 2, EP_PART = 3 };

template<int EPI>
__global__ __launch_bounds__(256, 2) void gemm_kernel(
    const unsigned short* __restrict__ A, const unsigned short* __restrict__ BT,
    void* __restrict__ outp, void* __restrict__ outp2, void* __restrict__ outp3,
    const unsigned short* __restrict__ up,  // EP_SILUMUL: u (bf16)
    const float* __restrict__ ct, const float* __restrict__ st,  // EP_QKV rope
    int M, int N, int K, int kspl)
{
    __shared__ unsigned short As[8192];   // 2 bufs x 128 x 32
    __shared__ unsigned short Bs[8192];
    const int tid = threadIdx.x;
    const int lane = tid & 63, wave = tid >> 6;

    // XCD-aware bijective block swizzle (nwg % 8 == 0 for all our grids)
    const int nwg = gridDim.x * gridDim.y;
    const int fid = blockIdx.y * gridDim.x + blockIdx.x;
    const int sid = (fid & 7) * (nwg >> 3) + (fid >> 3);
    const int m0 = (sid / gridDim.x) * 128;
    const int n0 = (sid % gridDim.x) * 128;
    const int kb0 = blockIdx.z * kspl;

    const int wr = (wave >> 1) * 64, wc = (wave & 1) * 64;
    const int lr = lane & 15, lg = lane >> 4;
    const int rcol = (lg ^ ((lr >> 1) & 3)) * 8;   // swizzled read chunk

    // staging sources (pre-swizzled chunk within each 64B row)
    const int cl0 = (wave * 2 + 0) * 64 + lane;
    const int cl1 = (wave * 2 + 1) * 64 + lane;
    const int r0 = cl0 >> 2, c0 = cl0 & 3;
    const int r1 = cl1 >> 2, c1 = cl1 & 3;
    const unsigned short* gA0 = A + (size_t)(m0 + r0) * K + kb0 + (c0 ^ ((r0 >> 1) & 3)) * 8;
    const unsigned short* gA1 = A + (size_t)(m0 + r1) * K + kb0 + (c1 ^ ((r1 >> 1) & 3)) * 8;
    const unsigned short* gB0 = BT + (size_t)(n0 + r0) * K + kb0 + (c0 ^ ((r0 >> 1) & 3)) * 8;
    const unsigned short* gB1 = BT + (size_t)(n0 + r1) * K + kb0 + (c1 ^ ((r1 >> 1) & 3)) * 8;

    f32x4 acc[4][4];
    #pragma unroll
    for (int i = 0; i < 4; i++)
        #pragma unroll
        for (int j = 0; j < 4; j++) acc[i][j] = (f32x4){0.f, 0.f, 0.f, 0.f};

    const int nsteps = kspl >> 5;   // always even here

    auto stage = [&](int buf, int kofs) {
        unsigned short* la = As + buf * 4096 + wave * 1024;
        unsigned short* lb = Bs + buf * 4096 + wave * 1024;
        async_copy16(gA0 + kofs, la);
        async_copy16(gA1 + kofs, la + 512);
        async_copy16(gB0 + kofs, lb);
        async_copy16(gB1 + kofs, lb + 512);
    };
    auto dostep = [&](int t, int cur) {
        if (t + 1 < nsteps) stage(cur ^ 1, (t + 1) * 32);
        const unsigned short* ab = As + cur * 4096;
        const unsigned short* bb = Bs + cur * 4096;
        short8 af[4], bfr[4];
        #pragma unroll
        for (int i = 0; i < 4; i++)
            af[i] = *(const short8*)&ab[(wr + i * 16 + lr) * 32 + rcol];
        #pragma unroll
        for (int j = 0; j < 4; j++)
            bfr[j] = *(const short8*)&bb[(wc + j * 16 + lr) * 32 + rcol];
        #pragma unroll
        for (int i = 0; i < 4; i++)
            #pragma unroll
            for (int j = 0; j < 4; j++)
                acc[i][j] = MFMA16(af[i], bfr[j], acc[i][j]);
        __syncthreads();   // drains own stage vmcnt + all ds_reads
    };

    stage(0, 0);
    __syncthreads();
    for (int t = 0; t < nsteps; t += 2) { dostep(t, 0); dostep(t + 1, 1); }

    // Epilogue.  D layout: row = (lane>>4)*4 + reg, col = lane&15.
    #pragma unroll
    for (int i = 0; i < 4; i++) {
        #pragma unroll
        for (int j = 0; j < 4; j++) {
            const int rb = m0 + wr + i * 16 + lg * 4;
            const int c  = n0 + wc + j * 16 + lr;
            if constexpr (EPI == EP_QKV) {
                if (n0 < 3072) {        // Q or K: fused RoPE
                    const int crel = (n0 < 2048) ? c : (c - 2048);
                    const int dd = crel & 127;
                    const int pr = dd >> 1;
                    #pragma unroll
                    for (int r = 0; r < 4; r++) {
                        const float v = acc[i][j][r];
                        const float p = __shfl_xor(v, 1);
                        const float cs = ct[(rb + r) * 64 + pr];
                        const float sn = st[(rb + r) * 64 + pr];
                        const float res = (dd & 1) ? (p * sn + v * cs) : (v * cs - p * sn);
                        if (n0 < 2048)
                            ((unsigned short*)outp)[(size_t)(rb + r) * 2048 + crel] = f2b_bits(res);
                        else
                            ((unsigned short*)outp2)[(size_t)(rb + r) * 1024 + crel] = f2b_bits(res);
                    }
                } else {                // V -> vT [1024][S] (transposed)
                    u16x4 pk4;
                    #pragma unroll
                    for (int r = 0; r < 4; r++) pk4[r] = f2b_bits(acc[i][j][r]);
                    *(u16x4*)((unsigned short*)outp3 + (size_t)(c - 3072) * 2048 + rb) = pk4;
                }
            } else if constexpr (EPI == EP_PART) {
                float* pout = (float*)outp + (size_t)blockIdx.z * M * N;
                #pragma unroll
                for (int r = 0; r < 4; r++)
                    pout[(size_t)(rb + r) * N + c] = acc[i][j][r];
            } else {
                #pragma unroll
                for (int r = 0; r < 4; r++) {
                    const size_t idx = (size_t)(rb + r) * N + c;
                    if constexpr (EPI == EP_BF16) {
                        ((unsigned short*)outp)[idx] = f2b_bits(acc[i][j][r]);
                    } else {  // EP_SILUMUL
                        const float uu = b2f_bits(up[idx]);
                        ((unsigned short*)outp)[idx] = f2b_bits(silu_f(uu) * acc[i][j][r]);
                    }
                }
            }
        }
    }
}

// ---------------------------------------------------------------------------
// W2 split-K combine (deterministic fixed-order sum)
// ---------------------------------------------------------------------------
__global__ void combine_w2(const float* __restrict__ p, float* __restrict__ out)
{
    const size_t i = ((size_t)blockIdx.x * 256 + threadIdx.x) * 4;
    const float4 a = *(const float4*)(p + i);
    const float4 b = *(const float4*)(p + (size_t)2048 * 2048 + i);
    float4 o = *(const float4*)(out + i);
    o.x += a.x + b.x; o.y += a.y + b.y; o.z += a.z + b.z; o.w += a.w + b.w;
    *(float4*)(out + i) = o;
}

// ---------------------------------------------------------------------------
// Flash attention, causal, GQA.  Round-5 variant (proven correct in r5):
// 4 waves = 2 heads x 2 q-subtiles, 1 kv-tile (64) per superstep,
// stage-ahead double buffer, no kv-split, no end-combine.
// Grid (8 kvh = XCD-pinned, 32 slabs LPT-desc).  32x32x16 MFMA, swapped QK^T.
// ---------------------------------------------------------------------------
__global__ __launch_bounds__(256, 2) void attn_kernel(
    const unsigned short* __restrict__ q,   // [S][2048] roped, pre-scaled
    const unsigned short* __restrict__ kk,  // [S][1024] roped
    const unsigned short* __restrict__ vT,  // [1024][S]
    unsigned short* __restrict__ o)         // [S][2048]
{
    __shared__ unsigned short Ks[2][8192];  // [buf][kv 64 x 128 shorts] 32KB
    __shared__ unsigned short Vs[2][8192];  // [buf][d 128 x 64 shorts]  32KB
    const int tid = threadIdx.x, wave = tid >> 6, lane = tid & 63;
    const int l5 = lane & 31, hi = lane >> 5;
    const int kvh = blockIdx.x;
    const int slab = 31 - blockIdx.y;       // LPT: big blocks dispatch first
    const int hs = wave >> 1, qs = wave & 1;
    const int h = kvh * 2 + hs;
    const int qrow = slab * 64 + qs * 32 + l5;
    const int ntiles = slab + 1;

    short8 qf[8];
    {
        const unsigned short* qp = q + (size_t)qrow * 2048 + h * 128 + hi * 8;
        #pragma unroll
        for (int kf = 0; kf < 8; kf++) qf[kf] = *(const short8*)(qp + kf * 16);
    }

    f32x16 ot[4];
    #pragma unroll
    for (int df = 0; df < 4; df++)
        #pragma unroll
        for (int r = 0; r < 16; r++) ot[df][r] = 0.0f;
    float m_ = -3e30f, l_ = 0.0f;

    auto stage = [&](int j, int b) {
        #pragma unroll
        for (int i = 0; i < 4; i++) {
            const int cl = (wave * 4 + i) * 64 + lane;      // [0,1024)
            const int row = cl >> 4, c = cl & 15;           // K: 64r x 16c
            async_copy16(kk + (size_t)(j * 64 + row) * 1024 + kvh * 128
                             + ((c ^ (row & 15)) * 8),
                         &Ks[b][(wave * 4 + i) * 512]);
        }
        #pragma unroll
        for (int i = 0; i < 4; i++) {
            const int cl = (wave * 4 + i) * 64 + lane;
            const int row = cl >> 3, c = cl & 7;            // V: 128r x 8c
            async_copy16(vT + (size_t)(kvh * 128 + row) * 2048 + j * 64
                             + ((c ^ (row & 7)) * 8),
                         &Vs[b][(wave * 4 + i) * 512]);
        }
    };

    stage(0, 0);
    __syncthreads();

    for (int j = 0; j < ntiles; ++j) {
        const int buf = j & 1;
        if (j + 1 < ntiles) stage(j + 1, buf ^ 1);
        const int kv0 = j * 64;
        // ---- QK^T (swapped) from swizzled LDS ----
        f32x16 st_[2];
        #pragma unroll
        for (int nf = 0; nf < 2; nf++)
            #pragma unroll
            for (int r = 0; r < 16; r++) st_[nf][r] = 0.0f;
        #pragma unroll
        for (int kf = 0; kf < 8; kf++) {
            const int ch = (kf * 2 + hi) ^ (l5 & 15);
            const short8 k0v = *(const short8*)&Ks[buf][l5 * 128 + ch * 8];
            const short8 k1v = *(const short8*)&Ks[buf][(l5 + 32) * 128 + ch * 8];
            st_[0] = MFMA32(k0v, qf[kf], st_[0]);
            st_[1] = MFMA32(k1v, qf[kf], st_[1]);
        }
        // ---- mask + online softmax (lane-local row) ----
        float sv[2][16];
        #pragma unroll
        for (int nf = 0; nf < 2; nf++)
            #pragma unroll
            for (int r = 0; r < 16; r++) {
                const int kvi = kv0 + nf * 32 + (r & 3) + 8 * (r >> 2) + 4 * hi;
                sv[nf][r] = (kvi > qrow) ? -3e30f : st_[nf][r];
            }
        float pmax = sv[0][0];
        #pragma unroll
        for (int nf = 0; nf < 2; nf++)
            #pragma unroll
            for (int r = 0; r < 16; r++) pmax = fmaxf(pmax, sv[nf][r]);
        pmax = fmaxf(pmax, __shfl_xor(pmax, 32));
        const float mnew = fmaxf(m_, pmax);
        const float alpha = __expf(m_ - mnew);
        m_ = mnew;
        float rs = 0.0f;
        #pragma unroll
        for (int nf = 0; nf < 2; nf++)
            #pragma unroll
            for (int r = 0; r < 16; r++) {
                const float p = __expf(sv[nf][r] - mnew);
                sv[nf][r] = p;
                rs += p;
            }
        rs += __shfl_xor(rs, 32);
        l_ = l_ * alpha + rs;
        #pragma unroll
        for (int df = 0; df < 4; df++)
            #pragma unroll
            for (int r = 0; r < 16; r++) ot[df][r] *= alpha;
        // ---- pack P to bf16 + cross-half exchange -> PV B-frags ----
        short8 pa[4];
        #pragma unroll
        for (int nf = 0; nf < 2; nf++) {
            #pragma unroll
            for (int hh = 0; hh < 2; hh++) {
                unsigned int a0 = ((unsigned int)f2b_bits(sv[nf][8 * hh + 1]) << 16) | f2b_bits(sv[nf][8 * hh + 0]);
                unsigned int a1 = ((unsigned int)f2b_bits(sv[nf][8 * hh + 3]) << 16) | f2b_bits(sv[nf][8 * hh + 2]);
                unsigned int a2 = ((unsigned int)f2b_bits(sv[nf][8 * hh + 5]) << 16) | f2b_bits(sv[nf][8 * hh + 4]);
                unsigned int a3 = ((unsigned int)f2b_bits(sv[nf][8 * hh + 7]) << 16) | f2b_bits(sv[nf][8 * hh + 6]);
                const unsigned int x0 = (unsigned int)__shfl_xor((int)a0, 32);
                const unsigned int x1 = (unsigned int)__shfl_xor((int)a1, 32);
                const unsigned int x2 = (unsigned int)__shfl_xor((int)a2, 32);
                const unsigned int x3 = (unsigned int)__shfl_xor((int)a3, 32);
                union { unsigned int u[4]; short8 s; } cv;
                cv.u[0] = hi ? x2 : a0;
                cv.u[1] = hi ? x3 : a1;
                cv.u[2] = hi ? a2 : x0;
                cv.u[3] = hi ? a3 : x1;
                pa[nf * 2 + hh] = cv.s;
            }
        }
        // ---- PV (swapped) from swizzled LDS ----
        #pragma unroll
        for (int df = 0; df < 4; df++) {
            const int d = df * 32 + l5;
            #pragma unroll
            for (int kvf = 0; kvf < 4; kvf++) {
                const int ch = (kvf * 2 + hi) ^ (d & 7);
                const short8 vfrag = *(const short8*)&Vs[buf][d * 64 + ch * 8];
                ot[df] = MFMA32(vfrag, pa[kvf], ot[df]);
            }
        }
        __syncthreads();
    }

    // ---- epilogue: normalize + store ----
    const float rinv = 1.0f / l_;
    #pragma unroll
    for (int df = 0; df < 4; df++) {
        #pragma unroll
        for (int g = 0; g < 4; g++) {
            u16x4 pk;
            #pragma unroll
            for (int e = 0; e < 4; e++)
                pk[e] = f2b_bits(ot[df][4 * g + e] * rinv);
            *(u16x4*)(o + (size_t)qrow * 2048 + h * 128 + df * 32 + 8 * g + 4 * hi) = pk;
        }
    }
}

// ---------------------------------------------------------------------------
extern "C" void kernel_launch(void* const* d_in, const int* in_sizes, int n_in,
                              void* d_out, int out_size, void* d_ws, size_t ws_size,
                              hipStream_t stream) {
    (void)in_sizes; (void)n_in; (void)out_size; (void)ws_size;
    const float* x     = (const float*)d_in[0];
    const float* vec   = (const float*)d_in[1];
    const float* cosb  = (const float*)d_in[2];
    const float* sinb  = (const float*)d_in[3];
    // d_in[4] = mask: causal, reproduced analytically
    const float* wq    = (const float*)d_in[5];
    const float* wk    = (const float*)d_in[6];
    const float* wv    = (const float*)d_in[7];
    const float* wo    = (const float*)d_in[8];
    const float* w1    = (const float*)d_in[9];
    const float* w2    = (const float*)d_in[10];
    const float* w3    = (const float*)d_in[11];
    const float* mod_w = (const float*)d_in[12];
    const float* mod_b = (const float*)d_in[13];
    const float* anw   = (const float*)d_in[14];
    const float* fnw   = (const float*)d_in[15];
    float* out = (float*)d_out;

    char* ws = (char*)d_ws;
    size_t off = 0;
    auto alloc = [&](size_t bytes) -> void* {
        void* p = ws + off; off += (bytes + 255) & ~(size_t)255; return p;
    };
    unsigned short* WTqkv = (unsigned short*)alloc((size_t)4096 * 2048 * 2); // [wq;wk;wv]
    unsigned short* WTo   = (unsigned short*)alloc((size_t)2048 * 2048 * 2);
    unsigned short* WT1   = (unsigned short*)alloc((size_t)5632 * 2048 * 2);
    unsigned short* WT3   = (unsigned short*)alloc((size_t)5632 * 2048 * 2);
    unsigned short* WT2   = (unsigned short*)alloc((size_t)2048 * 5632 * 2);
    float* part = (float*)alloc((size_t)64 * 6144 * 4);
    float* modb = (float*)alloc((size_t)8 * 6144 * 4);
    unsigned short* h    = (unsigned short*)alloc((size_t)2048 * 2048 * 2);  // also hn
    unsigned short* qb   = (unsigned short*)alloc((size_t)2048 * 2048 * 2);
    unsigned short* kb   = (unsigned short*)alloc((size_t)2048 * 1024 * 2);
    unsigned short* vT   = (unsigned short*)alloc((size_t)1024 * 2048 * 2);
    unsigned short* ob   = (unsigned short*)alloc((size_t)2048 * 2048 * 2);
    unsigned short* u    = (unsigned short*)alloc((size_t)2048 * 5632 * 2);
    unsigned short* ffin = (unsigned short*)alloc((size_t)2048 * 5632 * 2);

    // split-K partial buffers (reuse dead regions):
    float* pxg = (float*)u;   // free until W1 writes u
    float* pw2 = (float*)h;   // h..ob all dead once FFN inputs consumed

    const float qscale = 0.08838834764831845f;  // 1/sqrt(128) folded into Wq

    // Weights -> bf16 transposed (fused dispatches)
    transpose_qkv_kernel<<<dim3(64, 32), 256, 0, stream>>>(wq, wk, wv, WTqkv, qscale);
    transpose_kernel<<<dim3(32, 32), 256, 0, stream>>>(wo, WTo, 2048, 2048, 1.0f);
    transpose_w13_kernel<<<dim3(88, 32, 2), 256, 0, stream>>>(w1, w3, WT1, WT3);
    transpose_kernel<<<dim3(32, 88), 256, 0, stream>>>(w2, WT2, 5632, 2048, 1.0f);

    // Modulation (silu fused into mod_gemm1)
    mod_gemm1<<<dim3(24, 8), 256, 0, stream>>>(vec, mod_w, part);
    mod_gemm2<<<192, 256, 0, stream>>>(part, mod_b, modb);

    // h = (1+scale)*rmsnorm(x)*anw + shift   (bf16)
    norm_mod_kernel<<<2048, 256, 0, stream>>>(x, anw, modb, h);

    // Fused QKV GEMM (N=4096, 512 blocks) with fused RoPE epilogue
    gemm_kernel<EP_QKV><<<dim3(32, 16), 256, 0, stream>>>(
        h, WTqkv, qb, kb, vT, nullptr, cosb, sinb, 2048, 4096, 2048, 2048);

    // Attention (r5 variant: kvh XCD-pinned, 32 slabs LPT-desc)
    attn_kernel<<<dim3(8, 32), 256, 0, stream>>>(qb, kb, vT, ob);

    // o @ wo, split-K x2 -> f32 partials; fused combine+norm:
    //   out = x + gate*(p0+p1); h(=hn) = rmsnorm(out)*fnw
    gemm_kernel<EP_PART><<<dim3(16, 16, 2), 256, 0, stream>>>(
        ob, WTo, pxg, nullptr, nullptr, nullptr, nullptr, nullptr, 2048, 2048, 2048, 1024);
    combine_norm_kernel<<<2048, 256, 0, stream>>>(pxg, x, modb, fnw, out, h);

    // FFN: u = hn@w1 ; ffin = silu(u)*(hn@w3)
    gemm_kernel<EP_BF16><<<dim3(44, 16), 256, 0, stream>>>(
        h, WT1, u, nullptr, nullptr, nullptr, nullptr, nullptr, 2048, 5632, 2048, 2048);
    gemm_kernel<EP_SILUMUL><<<dim3(44, 16), 256, 0, stream>>>(
        h, WT3, ffin, nullptr, nullptr, u, nullptr, nullptr, 2048, 5632, 2048, 2048);

    // out += ffin @ w2, split-K x2 (K=5632 -> 2x2816)
    gemm_kernel<EP_PART><<<dim3(16, 16, 2), 256, 0, stream>>>(
        ffin, WT2, pw2, nullptr, nullptr, nullptr, nullptr, nullptr, 2048, 2048, 5632, 2816);
    combine_w2<<<4096, 256, 0, stream>>>(pw2, out);
}

// Round 17
// 444.769 us; speedup vs baseline: 1.0690x; 1.0690x over previous
//
#include <hip/hip_runtime.h>
#include <hip/hip_bf16.h>

// ---------------------------------------------------------------------------
// TokenFlowModel block on MI355X (gfx950).  FINAL = Round 13 (best: 446us).
// GEMMs: 128x128, BK=32, 2-phase double-buffer, XOR chunk swizzle (0 bank
//   conflicts), XCD-aware bijective block swizzle, split-K x2 for WO/W2,
//   RoPE fused in QKV epilogue.  (Measured optimum of this family: BK64,
//   3/4-buf counted-vmcnt, 256^2 8-phase, 64-row tiles, n-major raster,
//   bounds 3/4, r5-attn swap all tested and worse/null.)
// Attention: LDS-staged KV shared by 4 waves (2 heads x 2 kv-split),
//   swapped-QK^T lane-local softmax, XCD-pinned KV head, LPT order,
//   kv-split combine.  512 blocks.
// Elementwise: silu fused into mod_gemm1; combine+FFN-RMSNorm fused;
//   QKV / W1|W3 transposes dispatch-fused.
// ---------------------------------------------------------------------------

typedef __attribute__((ext_vector_type(8))) short short8;   // 8 x bf16
typedef __attribute__((ext_vector_type(4))) float f32x4;
typedef __attribute__((ext_vector_type(16))) float f32x16;
typedef __attribute__((ext_vector_type(4))) unsigned short u16x4;

#define MFMA16(a, b, c) __builtin_amdgcn_mfma_f32_16x16x32_bf16((a), (b), (c), 0, 0, 0)
#define MFMA32(a, b, c) __builtin_amdgcn_mfma_f32_32x32x16_bf16((a), (b), (c), 0, 0, 0)

__device__ __forceinline__ unsigned short f2b_bits(float f) {
    union { float f; unsigned int u; } cv; cv.f = f;
    unsigned int u = cv.u;
    u += 0x7fffu + ((u >> 16) & 1u);   // round-to-nearest-even
    return (unsigned short)(u >> 16);
}
__device__ __forceinline__ float b2f_bits(unsigned short b) {
    union { float f; unsigned int u; } cv; cv.u = ((unsigned int)b) << 16; return cv.f;
}
__device__ __forceinline__ float silu_f(float x) { return x / (1.0f + __expf(-x)); }

// async global->LDS, 16B per lane.  LDS dest: wave-uniform base + lane*16.
__device__ __forceinline__ void async_copy16(const unsigned short* g, unsigned short* l) {
    __builtin_amdgcn_global_load_lds(
        (const __attribute__((address_space(1))) unsigned int*)g,
        (__attribute__((address_space(3))) unsigned int*)l, 16, 0, 0);
}

// ---------------------------------------------------------------------------
// Transpose core: one 64x64 tile of W[K][N] f32 -> WT[N][K] bf16 (+scale)
// ---------------------------------------------------------------------------
__device__ __forceinline__ void transpose_tile(
    const float* __restrict__ W, unsigned short* __restrict__ WT,
    int K, int N, int k0, int n0, float scale, float t[64][65])
{
    const int tid = threadIdx.x;
    {
        const int row = tid >> 2, cq = (tid & 3) * 16;
        const float* src = W + (size_t)(k0 + row) * N + n0 + cq;
        #pragma unroll
        for (int i = 0; i < 4; i++) {
            float4 v = *(const float4*)(src + i * 4);
            t[row][cq + i * 4 + 0] = v.x;
            t[row][cq + i * 4 + 1] = v.y;
            t[row][cq + i * 4 + 2] = v.z;
            t[row][cq + i * 4 + 3] = v.w;
        }
    }
    __syncthreads();
    {
        const int n = tid >> 2, kq = (tid & 3) * 16;
        short8 v0, v1;
        #pragma unroll
        for (int i = 0; i < 8; i++) {
            v0[i] = (short)f2b_bits(t[kq + i][n] * scale);
            v1[i] = (short)f2b_bits(t[kq + 8 + i][n] * scale);
        }
        unsigned short* dst = WT + (size_t)(n0 + n) * K + k0 + kq;
        *(short8*)(dst) = v0;
        *(short8*)(dst + 8) = v1;
    }
}

__global__ __launch_bounds__(256) void transpose_kernel(
    const float* __restrict__ W, unsigned short* __restrict__ WT, int K, int N,
    float scale)
{
    __shared__ float t[64][65];
    transpose_tile(W, WT, K, N, blockIdx.y * 64, blockIdx.x * 64, scale, t);
}

// Fused QKV transpose: x<32 -> wq (scaled), 32<=x<48 -> wk, x>=48 -> wv.
__global__ __launch_bounds__(256) void transpose_qkv_kernel(
    const float* __restrict__ wq, const float* __restrict__ wk,
    const float* __restrict__ wv, unsigned short* __restrict__ WTqkv,
    float qscale)
{
    __shared__ float t[64][65];
    const int x = blockIdx.x, k0 = blockIdx.y * 64;
    if (x < 32) {
        transpose_tile(wq, WTqkv, 2048, 2048, k0, x * 64, qscale, t);
    } else if (x < 48) {
        transpose_tile(wk, WTqkv + (size_t)2048 * 2048, 2048, 1024, k0, (x - 32) * 64, 1.0f, t);
    } else {
        transpose_tile(wv, WTqkv + (size_t)3072 * 2048, 2048, 1024, k0, (x - 48) * 64, 1.0f, t);
    }
}

// Fused W1/W3 transpose via z.
__global__ __launch_bounds__(256) void transpose_w13_kernel(
    const float* __restrict__ w1, const float* __restrict__ w3,
    unsigned short* __restrict__ WT1, unsigned short* __restrict__ WT3)
{
    __shared__ float t[64][65];
    const float* W = blockIdx.z ? w3 : w1;
    unsigned short* WT = blockIdx.z ? WT3 : WT1;
    transpose_tile(W, WT, 2048, 5632, blockIdx.y * 64, blockIdx.x * 64, 1.0f, t);
}

// ---------------------------------------------------------------------------
// mod GEMM pass 1 (silu fused into the svec load): part[kc][m][6144]
// ---------------------------------------------------------------------------
__global__ __launch_bounds__(256) void mod_gemm1(
    const float* __restrict__ vec, const float* __restrict__ mw,
    float* __restrict__ part)
{
    __shared__ float svs[8][256];
    const int tid = threadIdx.x;
    const int nb = blockIdx.x, kc = blockIdx.y;
    const int n = nb * 256 + tid;
    #pragma unroll
    for (int m8 = 0; m8 < 8; m8++) svs[m8][tid] = silu_f(vec[m8 * 2048 + kc * 256 + tid]);
    __syncthreads();
    float acc[8];
    #pragma unroll
    for (int m = 0; m < 8; m++) acc[m] = 0.0f;
    for (int k = 0; k < 256; k++) {
        const float w = mw[(size_t)(kc * 256 + k) * 6144 + n];
        #pragma unroll
        for (int m = 0; m < 8; m++) acc[m] += svs[m][k] * w;
    }
    #pragma unroll
    for (int m = 0; m < 8; m++) part[(size_t)(kc * 8 + m) * 6144 + n] = acc[m];
}

__global__ void mod_gemm2(const float* __restrict__ part, const float* __restrict__ mb,
                          float* __restrict__ modb)
{
    const int i = blockIdx.x * 256 + threadIdx.x;   // 8*6144
    const int n = i % 6144;
    float a = mb[n];
    #pragma unroll
    for (int kc = 0; kc < 8; kc++) a += part[(size_t)(kc * 8 + (i / 6144)) * 6144 + n];
    modb[i] = a;
}

// ---------------------------------------------------------------------------
// RMSNorm + AdaLN modulation -> bf16 row.  One block per row.
// ---------------------------------------------------------------------------
__global__ __launch_bounds__(256) void norm_mod_kernel(
    const float* __restrict__ xin, const float* __restrict__ w,
    const float* __restrict__ mod, unsigned short* __restrict__ outp)
{
    const int s = blockIdx.x, tid = threadIdx.x;
    const float* xr = xin + (size_t)s * 2048;
    float4 a4 = *(const float4*)(xr + tid * 8);
    float4 b4 = *(const float4*)(xr + tid * 8 + 4);
    float v[8] = {a4.x, a4.y, a4.z, a4.w, b4.x, b4.y, b4.z, b4.w};
    float ss = 0.0f;
    #pragma unroll
    for (int i = 0; i < 8; i++) ss += v[i] * v[i];
    #pragma unroll
    for (int off = 1; off < 64; off <<= 1) ss += __shfl_xor(ss, off);
    __shared__ float red[4];
    if ((tid & 63) == 0) red[tid >> 6] = ss;
    __syncthreads();
    ss = red[0] + red[1] + red[2] + red[3];
    const float inv = rsqrtf(ss * (1.0f / 2048.0f) + 1e-6f);
    const int g = s >> 8;
    #pragma unroll
    for (int i = 0; i < 8; i++) {
        const int d = tid * 8 + i;
        float y = v[i] * inv * w[d];
        y = y * (1.0f + mod[g * 6144 + 2048 + d]) + mod[g * 6144 + d];
        outp[(size_t)s * 2048 + d] = f2b_bits(y);
    }
}

// ---------------------------------------------------------------------------
// Fused: out = x + gate*(p0+p1) ;  hn = rmsnorm(out)*fnw  (one pass per row)
// ---------------------------------------------------------------------------
__global__ __launch_bounds__(256) void combine_norm_kernel(
    const float* __restrict__ p, const float* __restrict__ x,
    const float* __restrict__ modp, const float* __restrict__ fnw,
    float* __restrict__ out, unsigned short* __restrict__ hn)
{
    const int s = blockIdx.x, tid = threadIdx.x;
    const int g = s >> 8;
    const size_t base = (size_t)s * 2048 + tid * 8;
    float v[8];
    #pragma unroll
    for (int i = 0; i < 8; i += 4) {
        const float4 a  = *(const float4*)(p + base + i);
        const float4 b  = *(const float4*)(p + (size_t)2048 * 2048 + base + i);
        const float4 xv = *(const float4*)(x + base + i);
        const float4 gv = *(const float4*)(modp + g * 6144 + 4096 + tid * 8 + i);
        v[i + 0] = xv.x + gv.x * (a.x + b.x);
        v[i + 1] = xv.y + gv.y * (a.y + b.y);
        v[i + 2] = xv.z + gv.z * (a.z + b.z);
        v[i + 3] = xv.w + gv.w * (a.w + b.w);
    }
    *(float4*)(out + base)     = (float4){v[0], v[1], v[2], v[3]};
    *(float4*)(out + base + 4) = (float4){v[4], v[5], v[6], v[7]};
    float ss = 0.0f;
    #pragma unroll
    for (int i = 0; i < 8; i++) ss += v[i] * v[i];
    #pragma unroll
    for (int off = 1; off < 64; off <<= 1) ss += __shfl_xor(ss, off);
    __shared__ float red[4];
    if ((tid & 63) == 0) red[tid >> 6] = ss;
    __syncthreads();
    ss = red[0] + red[1] + red[2] + red[3];
    const float inv = rsqrtf(ss * (1.0f / 2048.0f) + 1e-6f);
    #pragma unroll
    for (int i = 0; i < 8; i++) {
        const int d = tid * 8 + i;
        hn[(size_t)s * 2048 + d] = f2b_bits(v[i] * inv * fnw[d]);
    }
}

// ---------------------------------------------------------------------------
// bf16 GEMM, 2-phase double-buffered (proven core).
// 128x128 tile, BK=32, gload_lds width-16, XOR chunk swizzle, XCD swizzle.
// ---------------------------------------------------------------------------
enum { EP_QKV = 0, EP_BF16 = 1, EP_SILUMUL = 2, EP_PART = 3 };

template<int EPI>
__global__ __launch_bounds__(256, 2) void gemm_kernel(
    const unsigned short* __restrict__ A, const unsigned short* __restrict__ BT,
    void* __restrict__ outp, void* __restrict__ outp2, void* __restrict__ outp3,
    const unsigned short* __restrict__ up,  // EP_SILUMUL: u (bf16)
    const float* __restrict__ ct, const float* __restrict__ st,  // EP_QKV rope
    int M, int N, int K, int kspl)
{
    __shared__ unsigned short As[8192];   // 2 bufs x 128 x 32
    __shared__ unsigned short Bs[8192];
    const int tid = threadIdx.x;
    const int lane = tid & 63, wave = tid >> 6;

    // XCD-aware bijective block swizzle (nwg % 8 == 0 for all our grids)
    const int nwg = gridDim.x * gridDim.y;
    const int fid = blockIdx.y * gridDim.x + blockIdx.x;
    const int sid = (fid & 7) * (nwg >> 3) + (fid >> 3);
    const int m0 = (sid / gridDim.x) * 128;
    const int n0 = (sid % gridDim.x) * 128;
    const int kb0 = blockIdx.z * kspl;

    const int wr = (wave >> 1) * 64, wc = (wave & 1) * 64;
    const int lr = lane & 15, lg = lane >> 4;
    const int rcol = (lg ^ ((lr >> 1) & 3)) * 8;   // swizzled read chunk

    // staging sources (pre-swizzled chunk within each 64B row)
    const int cl0 = (wave * 2 + 0) * 64 + lane;
    const int cl1 = (wave * 2 + 1) * 64 + lane;
    const int r0 = cl0 >> 2, c0 = cl0 & 3;
    const int r1 = cl1 >> 2, c1 = cl1 & 3;
    const unsigned short* gA0 = A + (size_t)(m0 + r0) * K + kb0 + (c0 ^ ((r0 >> 1) & 3)) * 8;
    const unsigned short* gA1 = A + (size_t)(m0 + r1) * K + kb0 + (c1 ^ ((r1 >> 1) & 3)) * 8;
    const unsigned short* gB0 = BT + (size_t)(n0 + r0) * K + kb0 + (c0 ^ ((r0 >> 1) & 3)) * 8;
    const unsigned short* gB1 = BT + (size_t)(n0 + r1) * K + kb0 + (c1 ^ ((r1 >> 1) & 3)) * 8;

    f32x4 acc[4][4];
    #pragma unroll
    for (int i = 0; i < 4; i++)
        #pragma unroll
        for (int j = 0; j < 4; j++) acc[i][j] = (f32x4){0.f, 0.f, 0.f, 0.f};

    const int nsteps = kspl >> 5;   // always even here

    auto stage = [&](int buf, int kofs) {
        unsigned short* la = As + buf * 4096 + wave * 1024;
        unsigned short* lb = Bs + buf * 4096 + wave * 1024;
        async_copy16(gA0 + kofs, la);
        async_copy16(gA1 + kofs, la + 512);
        async_copy16(gB0 + kofs, lb);
        async_copy16(gB1 + kofs, lb + 512);
    };
    auto dostep = [&](int t, int cur) {
        if (t + 1 < nsteps) stage(cur ^ 1, (t + 1) * 32);
        const unsigned short* ab = As + cur * 4096;
        const unsigned short* bb = Bs + cur * 4096;
        short8 af[4], bfr[4];
        #pragma unroll
        for (int i = 0; i < 4; i++)
            af[i] = *(const short8*)&ab[(wr + i * 16 + lr) * 32 + rcol];
        #pragma unroll
        for (int j = 0; j < 4; j++)
            bfr[j] = *(const short8*)&bb[(wc + j * 16 + lr) * 32 + rcol];
        #pragma unroll
        for (int i = 0; i < 4; i++)
            #pragma unroll
            for (int j = 0; j < 4; j++)
                acc[i][j] = MFMA16(af[i], bfr[j], acc[i][j]);
        __syncthreads();   // drains own stage vmcnt + all ds_reads
    };

    stage(0, 0);
    __syncthreads();
    for (int t = 0; t < nsteps; t += 2) { dostep(t, 0); dostep(t + 1, 1); }

    // Epilogue.  D layout: row = (lane>>4)*4 + reg, col = lane&15.
    #pragma unroll
    for (int i = 0; i < 4; i++) {
        #pragma unroll
        for (int j = 0; j < 4; j++) {
            const int rb = m0 + wr + i * 16 + lg * 4;
            const int c  = n0 + wc + j * 16 + lr;
            if constexpr (EPI == EP_QKV) {
                if (n0 < 3072) {        // Q or K: fused RoPE
                    const int crel = (n0 < 2048) ? c : (c - 2048);
                    const int dd = crel & 127;
                    const int pr = dd >> 1;
                    #pragma unroll
                    for (int r = 0; r < 4; r++) {
                        const float v = acc[i][j][r];
                        const float p = __shfl_xor(v, 1);
                        const float cs = ct[(rb + r) * 64 + pr];
                        const float sn = st[(rb + r) * 64 + pr];
                        const float res = (dd & 1) ? (p * sn + v * cs) : (v * cs - p * sn);
                        if (n0 < 2048)
                            ((unsigned short*)outp)[(size_t)(rb + r) * 2048 + crel] = f2b_bits(res);
                        else
                            ((unsigned short*)outp2)[(size_t)(rb + r) * 1024 + crel] = f2b_bits(res);
                    }
                } else {                // V -> vT [1024][S] (transposed)
                    u16x4 pk4;
                    #pragma unroll
                    for (int r = 0; r < 4; r++) pk4[r] = f2b_bits(acc[i][j][r]);
                    *(u16x4*)((unsigned short*)outp3 + (size_t)(c - 3072) * 2048 + rb) = pk4;
                }
            } else if constexpr (EPI == EP_PART) {
                float* pout = (float*)outp + (size_t)blockIdx.z * M * N;
                #pragma unroll
                for (int r = 0; r < 4; r++)
                    pout[(size_t)(rb + r) * N + c] = acc[i][j][r];
            } else {
                #pragma unroll
                for (int r = 0; r < 4; r++) {
                    const size_t idx = (size_t)(rb + r) * N + c;
                    if constexpr (EPI == EP_BF16) {
                        ((unsigned short*)outp)[idx] = f2b_bits(acc[i][j][r]);
                    } else {  // EP_SILUMUL
                        const float uu = b2f_bits(up[idx]);
                        ((unsigned short*)outp)[idx] = f2b_bits(silu_f(uu) * acc[i][j][r]);
                    }
                }
            }
        }
    }
}

// ---------------------------------------------------------------------------
// W2 split-K combine (deterministic fixed-order sum)
// ---------------------------------------------------------------------------
__global__ void combine_w2(const float* __restrict__ p, float* __restrict__ out)
{
    const size_t i = ((size_t)blockIdx.x * 256 + threadIdx.x) * 4;
    const float4 a = *(const float4*)(p + i);
    const float4 b = *(const float4*)(p + (size_t)2048 * 2048 + i);
    float4 o = *(const float4*)(out + i);
    o.x += a.x + b.x; o.y += a.y + b.y; o.z += a.z + b.z; o.w += a.w + b.w;
    *(float4*)(out + i) = o;
}

// ---------------------------------------------------------------------------
// Flash attention, causal, GQA.  (proven r13 version: kv-split, 512 blocks)
// ---------------------------------------------------------------------------
__global__ __launch_bounds__(256, 2) void attn_kernel(
    const unsigned short* __restrict__ q,   // [S][2048] roped, pre-scaled
    const unsigned short* __restrict__ kk,  // [S][1024] roped
    const unsigned short* __restrict__ vT,  // [1024][S]
    unsigned short* __restrict__ o)         // [S][2048]
{
    __shared__ unsigned short Ks[2][8192];  // [tile][kv 64 x 128 shorts] 32KB
    __shared__ unsigned short Vs[2][8192];  // [tile][d 128 x 64 shorts]  32KB
    const int tid = threadIdx.x, wave = tid >> 6, lane = tid & 63;
    const int l5 = lane & 31, hi = lane >> 5;
    const int kvh = blockIdx.x;
    const int qt  = 63 - blockIdx.y;        // LPT: big blocks dispatch first
    const int hs = wave >> 1, ks = wave & 1;
    const int h = kvh * 2 + hs;
    const int q0 = qt * 32;
    const int qrow = q0 + l5;
    const int niter = (qt >> 1) + 1;        // 64-kv tiles needed
    const int nss = (niter + 1) >> 1;

    short8 qf[8];
    {
        const unsigned short* qp = q + (size_t)qrow * 2048 + h * 128 + hi * 8;
        #pragma unroll
        for (int kf = 0; kf < 8; kf++) qf[kf] = *(const short8*)(qp + kf * 16);
    }

    f32x16 ot[4];
    #pragma unroll
    for (int df = 0; df < 4; df++)
        #pragma unroll
        for (int r = 0; r < 16; r++) ot[df][r] = 0.0f;
    float m_ = -3e30f, l_ = 0.0f;

    for (int ss = 0; ss < nss; ss++) {
        const int kvA = ss * 128;
        #pragma unroll
        for (int t = 0; t < 2; t++) {
            #pragma unroll
            for (int i = 0; i < 4; i++) {
                const int cl = (wave * 4 + i) * 64 + lane;      // [0,1024)
                const int row = cl >> 4, c = cl & 15;           // K: 64r x 16c
                async_copy16(kk + (size_t)(kvA + t * 64 + row) * 1024 + kvh * 128
                                 + ((c ^ (row & 15)) * 8),
                             &Ks[t][(wave * 4 + i) * 512]);
            }
            #pragma unroll
            for (int i = 0; i < 4; i++) {
                const int cl = (wave * 4 + i) * 64 + lane;
                const int row = cl >> 3, c = cl & 7;            // V: 128r x 8c
                async_copy16(vT + (size_t)(kvh * 128 + row) * 2048 + kvA + t * 64
                                 + ((c ^ (row & 7)) * 8),
                             &Vs[t][(wave * 4 + i) * 512]);
            }
        }
        __syncthreads();

        const int j = 2 * ss + ks;
        if (j < niter) {
            const int kv0 = j * 64;
            f32x16 st_[2];
            #pragma unroll
            for (int nf = 0; nf < 2; nf++)
                #pragma unroll
                for (int r = 0; r < 16; r++) st_[nf][r] = 0.0f;
            #pragma unroll
            for (int kf = 0; kf < 8; kf++) {
                const int ch = (kf * 2 + hi) ^ (l5 & 15);
                const short8 k0v = *(const short8*)&Ks[ks][l5 * 128 + ch * 8];
                const short8 k1v = *(const short8*)&Ks[ks][(l5 + 32) * 128 + ch * 8];
                st_[0] = MFMA32(k0v, qf[kf], st_[0]);
                st_[1] = MFMA32(k1v, qf[kf], st_[1]);
            }
            float sv[2][16];
            #pragma unroll
            for (int nf = 0; nf < 2; nf++)
                #pragma unroll
                for (int r = 0; r < 16; r++) {
                    const int kvi = kv0 + nf * 32 + (r & 3) + 8 * (r >> 2) + 4 * hi;
                    sv[nf][r] = (kvi > qrow) ? -3e30f : st_[nf][r];
                }
            float pmax = sv[0][0];
            #pragma unroll
            for (int nf = 0; nf < 2; nf++)
                #pragma unroll
                for (int r = 0; r < 16; r++) pmax = fmaxf(pmax, sv[nf][r]);
            pmax = fmaxf(pmax, __shfl_xor(pmax, 32));
            const float mnew = fmaxf(m_, pmax);
            const float alpha = __expf(m_ - mnew);
            m_ = mnew;
            float rs = 0.0f;
            #pragma unroll
            for (int nf = 0; nf < 2; nf++)
                #pragma unroll
                for (int r = 0; r < 16; r++) {
                    const float p = __expf(sv[nf][r] - mnew);
                    sv[nf][r] = p;
                    rs += p;
                }
            rs += __shfl_xor(rs, 32);
            l_ = l_ * alpha + rs;
            #pragma unroll
            for (int df = 0; df < 4; df++)
                #pragma unroll
                for (int r = 0; r < 16; r++) ot[df][r] *= alpha;
            short8 pa[4];
            #pragma unroll
            for (int nf = 0; nf < 2; nf++) {
                #pragma unroll
                for (int hh = 0; hh < 2; hh++) {
                    unsigned int a0 = ((unsigned int)f2b_bits(sv[nf][8 * hh + 1]) << 16) | f2b_bits(sv[nf][8 * hh + 0]);
                    unsigned int a1 = ((unsigned int)f2b_bits(sv[nf][8 * hh + 3]) << 16) | f2b_bits(sv[nf][8 * hh + 2]);
                    unsigned int a2 = ((unsigned int)f2b_bits(sv[nf][8 * hh + 5]) << 16) | f2b_bits(sv[nf][8 * hh + 4]);
                    unsigned int a3 = ((unsigned int)f2b_bits(sv[nf][8 * hh + 7]) << 16) | f2b_bits(sv[nf][8 * hh + 6]);
                    const unsigned int x0 = (unsigned int)__shfl_xor((int)a0, 32);
                    const unsigned int x1 = (unsigned int)__shfl_xor((int)a1, 32);
                    const unsigned int x2 = (unsigned int)__shfl_xor((int)a2, 32);
                    const unsigned int x3 = (unsigned int)__shfl_xor((int)a3, 32);
                    union { unsigned int u[4]; short8 s; } cv;
                    cv.u[0] = hi ? x2 : a0;
                    cv.u[1] = hi ? x3 : a1;
                    cv.u[2] = hi ? a2 : x0;
                    cv.u[3] = hi ? a3 : x1;
                    pa[nf * 2 + hh] = cv.s;
                }
            }
            #pragma unroll
            for (int df = 0; df < 4; df++) {
                const int d = df * 32 + l5;
                #pragma unroll
                for (int kvf = 0; kvf < 4; kvf++) {
                    const int ch = (kvf * 2 + hi) ^ (d & 7);
                    const short8 vfrag = *(const short8*)&Vs[ks][d * 64 + ch * 8];
                    ot[df] = MFMA32(vfrag, pa[kvf], ot[df]);
                }
            }
        }
        __syncthreads();
    }

    float* Osh = (float*)&Ks[0][0];          // [2 heads][128 d][32 q] f32 = 32KB
    float* msh = (float*)&Vs[0][0];          // [2 heads][m(32) | l(32)]
    if (ks == 1) {
        #pragma unroll
        for (int df = 0; df < 4; df++)
            #pragma unroll
            for (int r = 0; r < 16; r++) {
                const int d = df * 32 + (r & 3) + 8 * (r >> 2) + 4 * hi;
                Osh[hs * 4096 + d * 32 + l5] = ot[df][r];
            }
        if (hi == 0) { msh[hs * 64 + l5] = m_; msh[hs * 64 + 32 + l5] = l_; }
    }
    __syncthreads();
    if (ks == 0) {
        const float m1 = msh[hs * 64 + l5], l1 = msh[hs * 64 + 32 + l5];
        const float mF = fmaxf(m_, m1);
        const float a0 = __expf(m_ - mF), a1 = __expf(m1 - mF);
        const float rinv = 1.0f / (l_ * a0 + l1 * a1);
        #pragma unroll
        for (int df = 0; df < 4; df++) {
            #pragma unroll
            for (int g = 0; g < 4; g++) {
                u16x4 pk;
                #pragma unroll
                for (int e = 0; e < 4; e++) {
                    const int d = df * 32 + e + 8 * g + 4 * hi;
                    const float ov = ot[df][4 * g + e] * a0 + Osh[hs * 4096 + d * 32 + l5] * a1;
                    pk[e] = f2b_bits(ov * rinv);
                }
                *(u16x4*)(o + (size_t)qrow * 2048 + h * 128 + df * 32 + 8 * g + 4 * hi) = pk;
            }
        }
    }
}

// ---------------------------------------------------------------------------
extern "C" void kernel_launch(void* const* d_in, const int* in_sizes, int n_in,
                              void* d_out, int out_size, void* d_ws, size_t ws_size,
                              hipStream_t stream) {
    (void)in_sizes; (void)n_in; (void)out_size; (void)ws_size;
    const float* x     = (const float*)d_in[0];
    const float* vec   = (const float*)d_in[1];
    const float* cosb  = (const float*)d_in[2];
    const float* sinb  = (const float*)d_in[3];
    // d_in[4] = mask: causal, reproduced analytically
    const float* wq    = (const float*)d_in[5];
    const float* wk    = (const float*)d_in[6];
    const float* wv    = (const float*)d_in[7];
    const float* wo    = (const float*)d_in[8];
    const float* w1    = (const float*)d_in[9];
    const float* w2    = (const float*)d_in[10];
    const float* w3    = (const float*)d_in[11];
    const float* mod_w = (const float*)d_in[12];
    const float* mod_b = (const float*)d_in[13];
    const float* anw   = (const float*)d_in[14];
    const float* fnw   = (const float*)d_in[15];
    float* out = (float*)d_out;

    char* ws = (char*)d_ws;
    size_t off = 0;
    auto alloc = [&](size_t bytes) -> void* {
        void* p = ws + off; off += (bytes + 255) & ~(size_t)255; return p;
    };
    unsigned short* WTqkv = (unsigned short*)alloc((size_t)4096 * 2048 * 2); // [wq;wk;wv]
    unsigned short* WTo   = (unsigned short*)alloc((size_t)2048 * 2048 * 2);
    unsigned short* WT1   = (unsigned short*)alloc((size_t)5632 * 2048 * 2);
    unsigned short* WT3   = (unsigned short*)alloc((size_t)5632 * 2048 * 2);
    unsigned short* WT2   = (unsigned short*)alloc((size_t)2048 * 5632 * 2);
    float* part = (float*)alloc((size_t)64 * 6144 * 4);
    float* modb = (float*)alloc((size_t)8 * 6144 * 4);
    unsigned short* h    = (unsigned short*)alloc((size_t)2048 * 2048 * 2);  // also hn
    unsigned short* qb   = (unsigned short*)alloc((size_t)2048 * 2048 * 2);
    unsigned short* kb   = (unsigned short*)alloc((size_t)2048 * 1024 * 2);
    unsigned short* vT   = (unsigned short*)alloc((size_t)1024 * 2048 * 2);
    unsigned short* ob   = (unsigned short*)alloc((size_t)2048 * 2048 * 2);
    unsigned short* u    = (unsigned short*)alloc((size_t)2048 * 5632 * 2);
    unsigned short* ffin = (unsigned short*)alloc((size_t)2048 * 5632 * 2);

    // split-K partial buffers (reuse dead regions):
    float* pxg = (float*)u;   // free until W1 writes u
    float* pw2 = (float*)h;   // h..ob all dead once FFN inputs consumed

    const float qscale = 0.08838834764831845f;  // 1/sqrt(128) folded into Wq

    // Weights -> bf16 transposed (fused dispatches)
    transpose_qkv_kernel<<<dim3(64, 32), 256, 0, stream>>>(wq, wk, wv, WTqkv, qscale);
    transpose_kernel<<<dim3(32, 32), 256, 0, stream>>>(wo, WTo, 2048, 2048, 1.0f);
    transpose_w13_kernel<<<dim3(88, 32, 2), 256, 0, stream>>>(w1, w3, WT1, WT3);
    transpose_kernel<<<dim3(32, 88), 256, 0, stream>>>(w2, WT2, 5632, 2048, 1.0f);

    // Modulation (silu fused into mod_gemm1)
    mod_gemm1<<<dim3(24, 8), 256, 0, stream>>>(vec, mod_w, part);
    mod_gemm2<<<192, 256, 0, stream>>>(part, mod_b, modb);

    // h = (1+scale)*rmsnorm(x)*anw + shift   (bf16)
    norm_mod_kernel<<<2048, 256, 0, stream>>>(x, anw, modb, h);

    // Fused QKV GEMM (N=4096, 512 blocks) with fused RoPE epilogue
    gemm_kernel<EP_QKV><<<dim3(32, 16), 256, 0, stream>>>(
        h, WTqkv, qb, kb, vT, nullptr, cosb, sinb, 2048, 4096, 2048, 2048);

    // Attention (kvh on blockIdx.x -> XCD-pinned KV; qt descending -> LPT)
    attn_kernel<<<dim3(8, 64), 256, 0, stream>>>(qb, kb, vT, ob);

    // o @ wo, split-K x2 -> f32 partials; fused combine+norm:
    //   out = x + gate*(p0+p1); h(=hn) = rmsnorm(out)*fnw
    gemm_kernel<EP_PART><<<dim3(16, 16, 2), 256, 0, stream>>>(
        ob, WTo, pxg, nullptr, nullptr, nullptr, nullptr, nullptr, 2048, 2048, 2048, 1024);
    combine_norm_kernel<<<2048, 256, 0, stream>>>(pxg, x, modb, fnw, out, h);

    // FFN: u = hn@w1 ; ffin = silu(u)*(hn@w3)
    gemm_kernel<EP_BF16><<<dim3(44, 16), 256, 0, stream>>>(
        h, WT1, u, nullptr, nullptr, nullptr, nullptr, nullptr, 2048, 5632, 2048, 2048);
    gemm_kernel<EP_SILUMUL><<<dim3(44, 16), 256, 0, stream>>>(
        h, WT3, ffin, nullptr, nullptr, u, nullptr, nullptr, 2048, 5632, 2048, 2048);

    // out += ffin @ w2, split-K x2 (K=5632 -> 2x2816)
    gemm_kernel<EP_PART><<<dim3(16, 16, 2), 256, 0, stream>>>(
        ffin, WT2, pw2, nullptr, nullptr, nullptr, nullptr, nullptr, 2048, 2048, 5632, 2816);
    combine_w2<<<4096, 256, 0, stream>>>(pw2, out);
}